// Round 10
// baseline (72.024 us; speedup 1.0000x reference)
//
#include <hip/hip_runtime.h>
#include <hip/hip_bf16.h>

typedef __attribute__((ext_vector_type(8))) __bf16 bf16x8;
typedef __attribute__((ext_vector_type(4))) float f32x4;
typedef __attribute__((ext_vector_type(8))) unsigned short ushort8;

__device__ __forceinline__ unsigned short f2bf(float f) {
  unsigned u = __builtin_bit_cast(unsigned, f);
  u += 0x7FFFu + ((u >> 16) & 1u);   // round-to-nearest-even
  return (unsigned short)(u >> 16);
}

__device__ __forceinline__ void gload_lds16(const void* g, void* l) {
  __builtin_amdgcn_global_load_lds(
      (const __attribute__((address_space(1))) void*)g,
      (__attribute__((address_space(3))) void*)l, 16, 0, 0);
}

__device__ __forceinline__ void barrier_fence() {
  __builtin_amdgcn_s_barrier();
  asm volatile("" ::: "memory");
}

template <int N>
__device__ __forceinline__ void waitvm() {
  if constexpr (N == 0)      asm volatile("s_waitcnt vmcnt(0)" ::: "memory");
  else if constexpr (N == 6) asm volatile("s_waitcnt vmcnt(6)" ::: "memory");
  else if constexpr (N == 8) asm volatile("s_waitcnt vmcnt(8)" ::: "memory");
}

// ---- prep: weight conversions ----
// [0,2048)    : U[4096][512] -> Ut[512][4096] bf16 (transpose)
// [2048,2560) : W[1024][512] -> Wt[512][1024] bf16 (transpose)
// [2560,3584) : V   (2M f32) -> Vb bf16
__global__ __launch_bounds__(256) void prep_kernel(
    const float* __restrict__ U, unsigned short* __restrict__ Ut,
    const float* __restrict__ W, unsigned short* __restrict__ Wt,
    const float* __restrict__ V, unsigned short* __restrict__ Vb) {
  __shared__ float tile[32][33];
  const int b = blockIdx.x;
  const int tid = threadIdx.x;
  if (b < 2560) {
    const float* src;
    unsigned short* dst;
    int rows, cols, bx, by;
    if (b < 2048) {
      src = U; dst = Ut; rows = 4096; cols = 512;
      bx = (b & 15) * 32; by = (b >> 4) * 32;
    } else {
      int bb = b - 2048;
      src = W; dst = Wt; rows = 1024; cols = 512;
      bx = (bb & 15) * 32; by = (bb >> 4) * 32;
    }
    const int tx = tid & 31, ty = tid >> 5;
    for (int i = ty; i < 32; i += 8)
      tile[i][tx] = src[(size_t)(by + i) * cols + bx + tx];
    __syncthreads();
    for (int i = ty; i < 32; i += 8)
      dst[(size_t)(bx + i) * rows + by + tx] = f2bf(tile[tx][i]);
  } else {
    const size_t i = (size_t)(b - 2560) * 256 + tid;  // 8 f32 per thread
    const float4* s4 = reinterpret_cast<const float4*>(V) + 2 * i;
    float4 a = s4[0], c = s4[1];
    ushort8 o;
    o[0] = f2bf(a.x); o[1] = f2bf(a.y); o[2] = f2bf(a.z); o[3] = f2bf(a.w);
    o[4] = f2bf(c.x); o[5] = f2bf(c.y); o[6] = f2bf(c.z); o[7] = f2bf(c.w);
    *(reinterpret_cast<ushort8*>(Vb) + i) = o;
  }
}

// ------------- GEMM core: 64xBN tile (FM=2), BK=64 -------------
// C = A[64,K] * Bt[BN,K]^T.  B bf16 via global_load_lds.
// AF32: A staged RAW F32 via global_load_lds (16B-chunk XOR swizzle,
// key=row&7), cvt to bf16 at fragment read.  !AF32: A bf16 classic.
// T4 counted-vmcnt 2-buffer pipeline (never drains vmcnt to 0 mid-loop).
// COLMAP: col-chunked XCD map (each XCD covers few B panels).
// EPI 0: outf[idx] = acc + e0[col]          (s = ctx@W + S)
// EPI 1: outb[idx] = bf16(acc * e0[idx])    (xus = xu * s)
// EPI 2: outf[idx] = relu(acc + e0[col])    (final)
template <int FM, int FN, int EPI, bool AF32, bool COLMAP>
__device__ __forceinline__ void gemm_core(
    const void* __restrict__ Av, const unsigned short* __restrict__ Bt,
    int N, int lda, int kchunk, const float* __restrict__ e0,
    float* __restrict__ outf, unsigned short* __restrict__ outb,
    int nwg, int bid) {
  static_assert(FM == 2, "A staging geometry assumes BM=64");
  constexpr int BM = 32 * FM, BN = 32 * FN, BK = 64;
  constexpr int ABYTES = BM * BK * (AF32 ? 4 : 2);   // 16KB or 8KB
  constexpr int AI = AF32 ? 4 : 2;
  constexpr int BI = BN / 32;
  constexpr int ISS = AI + BI;
  __shared__ __align__(16) char lds[2][ABYTES + BN * BK * 2];

  const int tid = threadIdx.x;
  const int wid = tid >> 6;
  const int lane = tid & 63;
  const int wr = wid >> 1, wc = wid & 1;

  // XCD-aware bijective swizzle (nwg % 8 == 0)
  const int swz = (bid & 7) * (nwg >> 3) + (bid >> 3);
  const int nbn = N / BN;
  int brow, bcol;
  if constexpr (COLMAP) {           // XCD chunk = few cols x all rows
    const int nbm = nwg / nbn;
    brow = (swz % nbm) * BM;
    bcol = (swz / nbm) * BN;
  } else {                          // XCD chunk = few rows x all cols
    brow = (swz / nbn) * BM;
    bcol = (swz % nbn) * BN;
  }

  f32x4 zero = {0.f, 0.f, 0.f, 0.f};
  f32x4 acc[FM][FN];
#pragma unroll
  for (int m = 0; m < FM; ++m)
#pragma unroll
    for (int n = 0; n < FN; ++n) acc[m][n] = zero;

  // bf16 staging: issue = 8 rows x 128B; phys 16B chunk c at row r holds
  // logical c^(r&7); source pre-swizzled.
  const int lr = lane >> 3;
  const int swzc = ((lane & 7) ^ lr) * 8;
  // f32 A staging: issue = 4 rows x 256B (16 x 16B chunks); key r&7 =
  // 4*(issue&1) + (lane>>4).
  const int a4r = lane >> 4;
  const int a4c = lane & 15;
  const int colE = ((a4c ^ a4r) << 2);
  const int colO = ((a4c ^ (4 + a4r)) << 2);

  const float* Agf =
      (const float*)Av + (size_t)(brow + wid * 16 + a4r) * lda;
  const unsigned short* Agh =
      (const unsigned short*)Av + (size_t)(brow + wid * 16 + lr) * lda + swzc;
  const unsigned short* Bgh =
      Bt + (size_t)(bcol + wid * (BN / 4) + lr) * lda + swzc;

  const int frow = lane & 15;
  const int fhi = lane >> 4;

  const int nsteps = kchunk / BK;

  auto stage = [&](int b, int kofs) {   // kofs in ELEMENTS (t*BK)
    char* dstA = lds[b] + wid * (AF32 ? 4096 : 2048);
    if constexpr (AF32) {
#pragma unroll
      for (int i = 0; i < 4; ++i)
        gload_lds16(Agf + kofs + (size_t)(4 * i) * lda + ((i & 1) ? colO : colE),
                    dstA + i * 1024);
    } else {
#pragma unroll
      for (int i = 0; i < 2; ++i)
        gload_lds16(Agh + kofs + (size_t)(8 * i) * lda, dstA + i * 1024);
    }
    char* dstB = lds[b] + ABYTES + wid * (BN * 32);
#pragma unroll
    for (int i = 0; i < BI; ++i)
      gload_lds16(Bgh + kofs + (size_t)(8 * i) * lda, dstB + i * 1024);
  };

  auto compute = [&](int cur) {
    const char* base = lds[cur];
    const unsigned short* Bs = (const unsigned short*)(base + ABYTES);
#pragma unroll
    for (int ks = 0; ks < 2; ++ks) {
      bf16x8 af[FM], bg[FN];
#pragma unroll
      for (int m = 0; m < FM; ++m) {
        int row = wr * FM * 16 + m * 16 + frow;
        int j = ks * 4 + fhi;
        if constexpr (AF32) {
          const float* ap = (const float*)base + row * 64;
          int r7 = row & 7;
          float4 lo = *(const float4*)(ap + (((2 * j) ^ r7) << 2));
          float4 hi = *(const float4*)(ap + (((2 * j + 1) ^ r7) << 2));
          bf16x8 tv;
          tv[0] = (__bf16)lo.x; tv[1] = (__bf16)lo.y;
          tv[2] = (__bf16)lo.z; tv[3] = (__bf16)lo.w;
          tv[4] = (__bf16)hi.x; tv[5] = (__bf16)hi.y;
          tv[6] = (__bf16)hi.z; tv[7] = (__bf16)hi.w;
          af[m] = tv;
        } else {
          int pc = j ^ (row & 7);
          af[m] = *(const bf16x8*)((const unsigned short*)base + row * 64 + pc * 8);
        }
      }
#pragma unroll
      for (int n = 0; n < FN; ++n) {
        int row = wc * FN * 16 + n * 16 + frow;
        int pc = (ks * 4 + fhi) ^ (row & 7);
        bg[n] = *(const bf16x8*)(Bs + row * 64 + pc * 8);
      }
#pragma unroll
      for (int m = 0; m < FM; ++m)
#pragma unroll
        for (int n = 0; n < FN; ++n)
          acc[m][n] = __builtin_amdgcn_mfma_f32_16x16x32_bf16(af[m], bg[n],
                                                              acc[m][n], 0, 0, 0);
    }
  };

  // prologue: tiles 0 and 1 in flight
  stage(0, 0);
  stage(1, BK);

  int cur = 0;
  for (int t = 0; t < nsteps; ++t) {
    if (t + 1 < nsteps)
      waitvm<ISS>();   // my portion of tile t landed
    else
      waitvm<0>();
    barrier_fence();   // ...for all waves
    compute(cur);
    if (t + 1 < nsteps) {
      asm volatile("s_waitcnt lgkmcnt(0)" ::: "memory");
      barrier_fence();                               // all waves done with cur
      if (t + 2 < nsteps) stage(cur, (t + 2) * BK);  // refill freed buffer
    }
    cur ^= 1;
  }

  // epilogue: D col = lane&15, row = (lane>>4)*4 + j
#pragma unroll
  for (int m = 0; m < FM; ++m) {
    int gr0 = brow + wr * FM * 16 + m * 16 + fhi * 4;
#pragma unroll
    for (int n = 0; n < FN; ++n) {
      int gc = bcol + wc * FN * 16 + n * 16 + frow;
#pragma unroll
      for (int j = 0; j < 4; ++j) {
        size_t idx = (size_t)(gr0 + j) * N + gc;
        float v = acc[m][n][j];
        if constexpr (EPI == 0) {
          outf[idx] = v + e0[gc];
        } else if constexpr (EPI == 1) {
          outb[idx] = f2bf(v * e0[idx]);
        } else {
          v += e0[gc];
          outf[idx] = v > 0.f ? v : 0.f;
        }
      }
    }
  }
}

// ---- s = S + context @ W   (M=2048, N=512, K=1024, f32 A direct) ----
__global__ __launch_bounds__(256) void sgemm_kernel(
    const float* __restrict__ ctx, const unsigned short* __restrict__ Wt,
    const float* __restrict__ S, float* __restrict__ sbuf) {
  gemm_core<2, 4, 0, true, false>(ctx, Wt, 512, 1024, 1024, S, sbuf, nullptr,
                                  128, (int)blockIdx.x);
}

// ---- xus = bf16((inputs @ U) * s)  (M=2048, N=512, K=4096, unsplit) ----
__global__ __launch_bounds__(256) void gemm1_kernel(
    const float* __restrict__ inp, const unsigned short* __restrict__ Ut,
    const float* __restrict__ sbuf, unsigned short* __restrict__ xus) {
  gemm_core<2, 2, 1, true, false>(inp, Ut, 512, 4096, 4096, sbuf, nullptr, xus,
                                  256, (int)blockIdx.x);
}

// ---- out = relu(xus @ V^T + bias)  (M=2048, N=4096, K=512, col-chunk map) ----
__global__ __launch_bounds__(256) void gemm2_kernel(
    const unsigned short* __restrict__ xus, const unsigned short* __restrict__ Vb,
    const float* __restrict__ bias, float* __restrict__ out) {
  gemm_core<2, 4, 2, false, true>(xus, Vb, 4096, 512, 512, bias, out, nullptr,
                                  1024, (int)blockIdx.x);
}

extern "C" void kernel_launch(void* const* d_in, const int* in_sizes, int n_in,
                              void* d_out, int out_size, void* d_ws, size_t ws_size,
                              hipStream_t stream) {
  constexpr int Bm = 2048, Nn = 4096, Cc = 1024, UU = 4096, RR = 512;
  const float* inputs  = (const float*)d_in[0];
  const float* context = (const float*)d_in[1];
  const float* U       = (const float*)d_in[2];
  const float* S       = (const float*)d_in[3];
  const float* V       = (const float*)d_in[4];
  const float* W       = (const float*)d_in[5];
  const float* bias    = (const float*)d_in[6];
  float* out = (float*)d_out;

  char* p = (char*)d_ws;
  unsigned short* Ut   = (unsigned short*)p; p += (size_t)RR * Nn * 2;   //  4 MB
  unsigned short* Wt   = (unsigned short*)p; p += (size_t)RR * Cc * 2;   //  1 MB
  unsigned short* Vb   = (unsigned short*)p; p += (size_t)UU * RR * 2;   //  4 MB
  float*          sbuf = (float*)p;          p += (size_t)Bm * RR * 4;   //  4 MB
  unsigned short* xus  = (unsigned short*)p; p += (size_t)Bm * RR * 2;   //  2 MB

  // 1) prep: U^T, W^T, V -> bf16
  prep_kernel<<<3584, 256, 0, stream>>>(U, Ut, W, Wt, V, Vb);

  // 2) s = S + context @ W   (f32 A staged directly)
  sgemm_kernel<<<128, 256, 0, stream>>>(context, Wt, S, sbuf);

  // 3) xus = bf16((inputs @ U) * s)   (no split-K, no partials)
  gemm1_kernel<<<256, 256, 0, stream>>>(inputs, Ut, sbuf, xus);

  // 4) out = relu(xus @ V^T + bias)
  gemm2_kernel<<<1024, 256, 0, stream>>>(xus, Vb, bias, out);
}

// Round 12
// 64.501 us; speedup vs baseline: 1.1166x; 1.1166x over previous
//
#include <hip/hip_runtime.h>
#include <hip/hip_bf16.h>

typedef __attribute__((ext_vector_type(8))) __bf16 bf16x8;
typedef __attribute__((ext_vector_type(4))) float f32x4;
typedef __attribute__((ext_vector_type(8))) unsigned short ushort8;
typedef __attribute__((ext_vector_type(4))) unsigned short ushort4v;

__device__ __forceinline__ unsigned short f2bf(float f) {
  unsigned u = __builtin_bit_cast(unsigned, f);
  u += 0x7FFFu + ((u >> 16) & 1u);   // round-to-nearest-even
  return (unsigned short)(u >> 16);
}

__device__ __forceinline__ void gload_lds16(const void* g, void* l) {
  __builtin_amdgcn_global_load_lds(
      (const __attribute__((address_space(1))) void*)g,
      (__attribute__((address_space(3))) void*)l, 16, 0, 0);
}

__device__ __forceinline__ void barrier_fence() {
  __builtin_amdgcn_s_barrier();
  asm volatile("" ::: "memory");
}

template <int N>
__device__ __forceinline__ void waitvm() {
  if constexpr (N == 0)       asm volatile("s_waitcnt vmcnt(0)" ::: "memory");
  else if constexpr (N == 6)  asm volatile("s_waitcnt vmcnt(6)" ::: "memory");
  else if constexpr (N == 8)  asm volatile("s_waitcnt vmcnt(8)" ::: "memory");
  else if constexpr (N == 12) asm volatile("s_waitcnt vmcnt(12)" ::: "memory");
}

// ---- prep: weight conversions ----
// [0,2048)    : U[4096][512] -> Ut[512][4096] bf16 (transpose)
// [2048,2560) : W[1024][512] -> Wt[512][1024] bf16 (transpose)
// [2560,3584) : V   (2M f32) -> Vb bf16
__global__ __launch_bounds__(256) void prep_kernel(
    const float* __restrict__ U, unsigned short* __restrict__ Ut,
    const float* __restrict__ W, unsigned short* __restrict__ Wt,
    const float* __restrict__ V, unsigned short* __restrict__ Vb) {
  __shared__ float tile[32][33];
  const int b = blockIdx.x;
  const int tid = threadIdx.x;
  if (b < 2560) {
    const float* src;
    unsigned short* dst;
    int rows, cols, bx, by;
    if (b < 2048) {
      src = U; dst = Ut; rows = 4096; cols = 512;
      bx = (b & 15) * 32; by = (b >> 4) * 32;
    } else {
      int bb = b - 2048;
      src = W; dst = Wt; rows = 1024; cols = 512;
      bx = (bb & 15) * 32; by = (bb >> 4) * 32;
    }
    const int tx = tid & 31, ty = tid >> 5;
    for (int i = ty; i < 32; i += 8)
      tile[i][tx] = src[(size_t)(by + i) * cols + bx + tx];
    __syncthreads();
    for (int i = ty; i < 32; i += 8)
      dst[(size_t)(bx + i) * rows + by + tx] = f2bf(tile[tx][i]);
  } else {
    const size_t i = (size_t)(b - 2560) * 256 + tid;  // 8 f32 per thread
    const float4* s4 = reinterpret_cast<const float4*>(V) + 2 * i;
    float4 a = s4[0], c = s4[1];
    ushort8 o;
    o[0] = f2bf(a.x); o[1] = f2bf(a.y); o[2] = f2bf(a.z); o[3] = f2bf(a.w);
    o[4] = f2bf(c.x); o[5] = f2bf(c.y); o[6] = f2bf(c.z); o[7] = f2bf(c.w);
    *(reinterpret_cast<ushort8*>(Vb) + i) = o;
  }
}

// ------------- GEMM core: 64xBN tile (FM=2), BK=64, DEPTH-buffer -------------
// C = A[64,K] * Bt[BN,K]^T.  B bf16 via global_load_lds.
// NOTE: caller passes A and Bt ALREADY OFFSET to the K-chunk start (both!).
// AF32: A staged RAW F32 via global_load_lds (16B-chunk XOR swizzle, key=row&7),
// cvt to bf16 at fragment read.  !AF32: A bf16 classic layout.
// T4 counted-vmcnt DEPTH-buffer pipeline: tile t's wait happens DEPTH-1
// steps after its stage -> cover = (DEPTH-1) full compute phases.
// Wait ledger: at step t, stages outstanding beyond tile t =
// min(DEPTH-1, nsteps-1-t); wait vmcnt(that * ISS).
// EPI 2: outf[idx] = relu(acc + e0[col]); EPI 3: outf[idx] = acc (partial).
template <int FN, int EPI, bool AF32, int DEPTH>
__device__ __forceinline__ void gemm_core(
    const void* __restrict__ Av, const unsigned short* __restrict__ Bt,
    int N, int lda, int kchunk, const float* __restrict__ e0,
    float* __restrict__ outf, int nwg, int bid) {
  constexpr int FM = 2;
  constexpr int BM = 32 * FM, BN = 32 * FN, BK = 64;
  constexpr int ABYTES = BM * BK * (AF32 ? 4 : 2);   // 16KB or 8KB
  constexpr int AI = AF32 ? 4 : 2;
  constexpr int BI = BN / 32;
  constexpr int ISS = AI + BI;
  __shared__ __align__(16) char lds[DEPTH][ABYTES + BN * BK * 2];

  const int tid = threadIdx.x;
  const int wid = tid >> 6;
  const int lane = tid & 63;
  const int wr = wid >> 1, wc = wid & 1;

  // XCD-aware bijective swizzle (nwg % 8 == 0)
  const int swz = (bid & 7) * (nwg >> 3) + (bid >> 3);
  const int nbn = N / BN;
  const int brow = (swz / nbn) * BM;
  const int bcol = (swz % nbn) * BN;

  f32x4 zero = {0.f, 0.f, 0.f, 0.f};
  f32x4 acc[FM][FN];
#pragma unroll
  for (int m = 0; m < FM; ++m)
#pragma unroll
    for (int n = 0; n < FN; ++n) acc[m][n] = zero;

  // bf16 staging: issue = 8 rows x 128B; phys 16B chunk c at row r holds
  // logical c^(r&7); source pre-swizzled.
  const int lr = lane >> 3;
  const int swzc = ((lane & 7) ^ lr) * 8;
  // f32 A staging: issue = 4 rows x 256B (16 x 16B chunks); key r&7 =
  // 4*(issue&1) + (lane>>4).
  const int a4r = lane >> 4;
  const int a4c = lane & 15;
  const int colE = ((a4c ^ a4r) << 2);
  const int colO = ((a4c ^ (4 + a4r)) << 2);

  const float* Agf =
      (const float*)Av + (size_t)(brow + wid * 16 + a4r) * lda;
  const unsigned short* Agh =
      (const unsigned short*)Av + (size_t)(brow + wid * 16 + lr) * lda + swzc;
  const unsigned short* Bgh =
      Bt + (size_t)(bcol + wid * (BN / 4) + lr) * lda + swzc;

  const int frow = lane & 15;
  const int fhi = lane >> 4;

  const int nsteps = kchunk / BK;   // >= DEPTH for all our shapes

  auto stage = [&](int b, int kofs) {   // kofs in ELEMENTS (t*BK)
    char* dstA = lds[b] + wid * (AF32 ? 4096 : 2048);
    if constexpr (AF32) {
#pragma unroll
      for (int i = 0; i < 4; ++i)
        gload_lds16(Agf + kofs + (size_t)(4 * i) * lda + ((i & 1) ? colO : colE),
                    dstA + i * 1024);
    } else {
#pragma unroll
      for (int i = 0; i < 2; ++i)
        gload_lds16(Agh + kofs + (size_t)(8 * i) * lda, dstA + i * 1024);
    }
    char* dstB = lds[b] + ABYTES + wid * (BN * 32);
#pragma unroll
    for (int i = 0; i < BI; ++i)
      gload_lds16(Bgh + kofs + (size_t)(8 * i) * lda, dstB + i * 1024);
  };

  auto compute = [&](int cur) {
    const char* base = lds[cur];
    const unsigned short* Bs = (const unsigned short*)(base + ABYTES);
#pragma unroll
    for (int ks = 0; ks < 2; ++ks) {
      bf16x8 af[FM], bg[FN];
#pragma unroll
      for (int m = 0; m < FM; ++m) {
        int row = wr * FM * 16 + m * 16 + frow;
        int j = ks * 4 + fhi;
        if constexpr (AF32) {
          const float* ap = (const float*)base + row * 64;
          int r7 = row & 7;
          float4 lo = *(const float4*)(ap + (((2 * j) ^ r7) << 2));
          float4 hi = *(const float4*)(ap + (((2 * j + 1) ^ r7) << 2));
          bf16x8 tv;
          tv[0] = (__bf16)lo.x; tv[1] = (__bf16)lo.y;
          tv[2] = (__bf16)lo.z; tv[3] = (__bf16)lo.w;
          tv[4] = (__bf16)hi.x; tv[5] = (__bf16)hi.y;
          tv[6] = (__bf16)hi.z; tv[7] = (__bf16)hi.w;
          af[m] = tv;
        } else {
          int pc = j ^ (row & 7);
          af[m] = *(const bf16x8*)((const unsigned short*)base + row * 64 + pc * 8);
        }
      }
#pragma unroll
      for (int n = 0; n < FN; ++n) {
        int row = wc * FN * 16 + n * 16 + frow;
        int pc = (ks * 4 + fhi) ^ (row & 7);
        bg[n] = *(const bf16x8*)(Bs + row * 64 + pc * 8);
      }
#pragma unroll
      for (int m = 0; m < FM; ++m)
#pragma unroll
        for (int n = 0; n < FN; ++n)
          acc[m][n] = __builtin_amdgcn_mfma_f32_16x16x32_bf16(af[m], bg[n],
                                                              acc[m][n], 0, 0, 0);
    }
  };

  // prologue: DEPTH tiles in flight
#pragma unroll
  for (int d = 0; d < DEPTH; ++d) stage(d, d * BK);

  int cur = 0;
  for (int t = 0; t < nsteps; ++t) {
    const int ahead = nsteps - 1 - t;      // stages outstanding beyond tile t
    if (ahead >= DEPTH - 1)
      waitvm<(DEPTH - 1) * ISS>();         // tile t landed (my portion)
    else if (ahead >= 1)
      waitvm<ISS>();
    else
      waitvm<0>();
    barrier_fence();                       // ...for all waves
    compute(cur);
    if (t + 1 < nsteps) {
      asm volatile("s_waitcnt lgkmcnt(0)" ::: "memory");
      barrier_fence();                     // all waves done reading cur
      if (t + DEPTH < nsteps) stage(cur, (t + DEPTH) * BK);
    }
    cur = (cur + 1 == DEPTH) ? 0 : cur + 1;
  }

  // epilogue: D col = lane&15, row = (lane>>4)*4 + j
#pragma unroll
  for (int m = 0; m < FM; ++m) {
    int gr0 = brow + wr * FM * 16 + m * 16 + fhi * 4;
#pragma unroll
    for (int n = 0; n < FN; ++n) {
      int gc = bcol + wc * FN * 16 + n * 16 + frow;
#pragma unroll
      for (int j = 0; j < 4; ++j) {
        size_t idx = (size_t)(gr0 + j) * N + gc;
        float v = acc[m][n][j];
        if constexpr (EPI == 2) {
          v += e0[gc];
          outf[idx] = v > 0.f ? v : 0.f;
        } else {
          outf[idx] = v;
        }
      }
    }
  }
}

// ---- merged split-K partial GEMMs, A = f32 direct, 64x64 tiles, DEPTH=3 ----
// blocks [0,1024)    : inputs@U  (lda 4096, kchunk 1024, split 4) -> p1
// blocks [1024,1536) : context@W (lda 1024, kchunk  512, split 2) -> p0
// K-chunk offset applied to BOTH A and Bt at the call site.
__global__ __launch_bounds__(256) void gemm01_kernel(
    const float* __restrict__ inp, const unsigned short* __restrict__ Ut,
    const float* __restrict__ ctx, const unsigned short* __restrict__ Wt,
    float* __restrict__ p0, float* __restrict__ p1) {
  const int bid = (int)blockIdx.x;
  constexpr size_t MN = (size_t)2048 * 512;
  if (bid < 1024) {
    const int split = bid >> 8;          // 4 splits x 256 positions
    gemm_core<2, 3, true, 3>(inp + (size_t)split * 1024,
                             Ut + (size_t)split * 1024,
                             512, 4096, 1024, nullptr,
                             p1 + split * MN, 256, bid & 255);
  } else {
    const int sb = bid - 1024;
    const int split = sb >> 8;           // 2 splits x 256 positions
    gemm_core<2, 3, true, 3>(ctx + (size_t)split * 512,
                             Wt + (size_t)split * 512,
                             512, 1024, 512, nullptr,
                             p0 + split * MN, 256, sb & 255);
  }
}

// ---- final GEMM: out = relu(xus @ V^T + bias), all-bf16, 64x128, DEPTH=2 ----
__global__ __launch_bounds__(256) void gemm2_kernel(
    const unsigned short* __restrict__ xus, const unsigned short* __restrict__ Vb,
    const float* __restrict__ bias, float* __restrict__ out) {
  gemm_core<4, 2, false, 2>(xus, Vb, 4096, 512, 512, bias, out, 1024,
                            (int)blockIdx.x);
}

// ---- fused split-K reduce: xus = bf16((sum p1) * (S + sum p0)) ----
__global__ void reduce_mul_kernel(const float* __restrict__ p1,  // [4][MN]
                                  const float* __restrict__ p0,  // [2][MN]
                                  const float* __restrict__ Svec,  // [512]
                                  unsigned short* __restrict__ xus, int MN) {
  int i = blockIdx.x * blockDim.x + threadIdx.x;
  size_t base = (size_t)i * 4;
  if (base >= (size_t)MN) return;
  float4 a = *reinterpret_cast<const float4*>(p1 + base);
  float4 b = *reinterpret_cast<const float4*>(p1 + (size_t)MN + base);
  float4 c = *reinterpret_cast<const float4*>(p1 + 2 * (size_t)MN + base);
  float4 d = *reinterpret_cast<const float4*>(p1 + 3 * (size_t)MN + base);
  float4 s0 = *reinterpret_cast<const float4*>(p0 + base);
  float4 s1 = *reinterpret_cast<const float4*>(p0 + (size_t)MN + base);
  float4 sv = *reinterpret_cast<const float4*>(Svec + (base & 511));
  float4 xu, s;
  xu.x = (a.x + b.x) + (c.x + d.x);  s.x = s0.x + s1.x + sv.x;
  xu.y = (a.y + b.y) + (c.y + d.y);  s.y = s0.y + s1.y + sv.y;
  xu.z = (a.z + b.z) + (c.z + d.z);  s.z = s0.z + s1.z + sv.z;
  xu.w = (a.w + b.w) + (c.w + d.w);  s.w = s0.w + s1.w + sv.w;
  ushort4v o;
  o[0] = f2bf(xu.x * s.x);
  o[1] = f2bf(xu.y * s.y);
  o[2] = f2bf(xu.z * s.z);
  o[3] = f2bf(xu.w * s.w);
  *reinterpret_cast<ushort4v*>(xus + base) = o;
}

extern "C" void kernel_launch(void* const* d_in, const int* in_sizes, int n_in,
                              void* d_out, int out_size, void* d_ws, size_t ws_size,
                              hipStream_t stream) {
  constexpr int Bm = 2048, Nn = 4096, Cc = 1024, UU = 4096, RR = 512;
  const float* inputs  = (const float*)d_in[0];
  const float* context = (const float*)d_in[1];
  const float* U       = (const float*)d_in[2];
  const float* S       = (const float*)d_in[3];
  const float* V       = (const float*)d_in[4];
  const float* W       = (const float*)d_in[5];
  const float* bias    = (const float*)d_in[6];
  float* out = (float*)d_out;

  char* p = (char*)d_ws;
  unsigned short* Ut   = (unsigned short*)p; p += (size_t)RR * Nn * 2;      //  4 MB
  unsigned short* Wt   = (unsigned short*)p; p += (size_t)RR * Cc * 2;      //  1 MB
  unsigned short* Vb   = (unsigned short*)p; p += (size_t)UU * RR * 2;      //  4 MB
  float*          p0   = (float*)p;          p += (size_t)2 * Bm * RR * 4;  //  8 MB
  float*          p1   = (float*)p;          p += (size_t)4 * Bm * RR * 4;  // 16 MB
  unsigned short* xus  = (unsigned short*)p; p += (size_t)Bm * RR * 2;      //  2 MB

  // 1) prep: U^T, W^T, V -> bf16
  prep_kernel<<<3584, 256, 0, stream>>>(U, Ut, W, Wt, V, Vb);

  // 2) merged split-K partials from f32 A (DEPTH=3 pipeline, 64x64 tiles)
  gemm01_kernel<<<1536, 256, 0, stream>>>(inputs, Ut, context, Wt, p0, p1);

  // 3) xus = bf16((sum p1) * (S + sum p0))
  reduce_mul_kernel<<<Bm * RR / 4 / 256, 256, 0, stream>>>(p1, p0, S, xus, Bm * RR);

  // 4) out = relu(xus @ V^T + bias)   (M=2048, N=4096, K=512, 64x128 tiles)
  gemm2_kernel<<<1024, 256, 0, stream>>>(xus, Vb, bias, out);
}

// Round 13
// 54.202 us; speedup vs baseline: 1.3288x; 1.1900x over previous
//
#include <hip/hip_runtime.h>
#include <hip/hip_bf16.h>

typedef __attribute__((ext_vector_type(8))) __bf16 bf16x8;
typedef __attribute__((ext_vector_type(4))) float f32x4;
typedef __attribute__((ext_vector_type(8))) unsigned short ushort8;
typedef __attribute__((ext_vector_type(4))) unsigned short ushort4v;

__device__ __forceinline__ unsigned short f2bf(float f) {
  unsigned u = __builtin_bit_cast(unsigned, f);
  u += 0x7FFFu + ((u >> 16) & 1u);   // round-to-nearest-even
  return (unsigned short)(u >> 16);
}

__device__ __forceinline__ void gload_lds16(const void* g, void* l) {
  __builtin_amdgcn_global_load_lds(
      (const __attribute__((address_space(1))) void*)g,
      (__attribute__((address_space(3))) void*)l, 16, 0, 0);
}

__device__ __forceinline__ void barrier_fence() {
  __builtin_amdgcn_s_barrier();
  asm volatile("" ::: "memory");
}

template <int N>
__device__ __forceinline__ void waitvm() {
  if constexpr (N == 0)       asm volatile("s_waitcnt vmcnt(0)" ::: "memory");
  else if constexpr (N == 8)  asm volatile("s_waitcnt vmcnt(8)" ::: "memory");
  else if constexpr (N == 16) asm volatile("s_waitcnt vmcnt(16)" ::: "memory");
}

// ---- prep: all operand conversions in ONE launch (round-6 verbatim) ----
// [0,2048)    : U[4096][512] -> Ut[512][4096] bf16 (transpose)
// [2048,2560) : W[1024][512] -> Wt[512][1024] bf16 (transpose)
// [2560,3584) : V   (2M f32) -> Vb bf16
// [3584,7680) : inputs (8M)  -> inb bf16
// [7680,8704) : context (2M) -> ctxb bf16
__global__ __launch_bounds__(256) void prep_kernel(
    const float* __restrict__ U, unsigned short* __restrict__ Ut,
    const float* __restrict__ W, unsigned short* __restrict__ Wt,
    const float* __restrict__ V, unsigned short* __restrict__ Vb,
    const float* __restrict__ inp, unsigned short* __restrict__ inb,
    const float* __restrict__ ctx, unsigned short* __restrict__ ctxb) {
  __shared__ float tile[32][33];
  const int b = blockIdx.x;
  const int tid = threadIdx.x;
  if (b < 2560) {
    const float* src;
    unsigned short* dst;
    int rows, cols, bx, by;
    if (b < 2048) {
      src = U; dst = Ut; rows = 4096; cols = 512;
      bx = (b & 15) * 32; by = (b >> 4) * 32;
    } else {
      int bb = b - 2048;
      src = W; dst = Wt; rows = 1024; cols = 512;
      bx = (bb & 15) * 32; by = (bb >> 4) * 32;
    }
    const int tx = tid & 31, ty = tid >> 5;
    for (int i = ty; i < 32; i += 8)
      tile[i][tx] = src[(size_t)(by + i) * cols + bx + tx];
    __syncthreads();
    for (int i = ty; i < 32; i += 8)
      dst[(size_t)(bx + i) * rows + by + tx] = f2bf(tile[tx][i]);
  } else {
    const float* src;
    unsigned short* dst;
    size_t i;
    if (b < 3584)      { src = V;   dst = Vb;   i = (size_t)(b - 2560) * 256 + tid; }
    else if (b < 7680) { src = inp; dst = inb;  i = (size_t)(b - 3584) * 256 + tid; }
    else               { src = ctx; dst = ctxb; i = (size_t)(b - 7680) * 256 + tid; }
    const float4* s4 = reinterpret_cast<const float4*>(src) + 2 * i;
    float4 a = s4[0], c = s4[1];
    ushort8 o;
    o[0] = f2bf(a.x); o[1] = f2bf(a.y); o[2] = f2bf(a.z); o[3] = f2bf(a.w);
    o[4] = f2bf(c.x); o[5] = f2bf(c.y); o[6] = f2bf(c.z); o[7] = f2bf(c.w);
    *(reinterpret_cast<ushort8*>(dst) + i) = o;
  }
}

// -------- bf16 GEMM core: BMxBN tile, BK=64, counted-vmcnt DEPTH=2 --------
// m97-class geometry at FM=FN=4: 128x128 tile, 4 waves, each wave owns a
// 64x64 quadrant (acc[4][4] => 32 MFMA per K-step per wave).
// Caller passes A and Bt ALREADY OFFSET to the K-chunk start (both!).
// Staging: 1KB issues via global_load_lds; XOR swizzle: phys 16B chunk c at
// row r holds logical c^(r&7) (source pre-swizzled, read applies ^(r&7)).
// Wait ledger: at step t, stages outstanding beyond t = min(DEPTH-1, ahead);
// wait vmcnt(that * ISS), ISS = FM + FN loads/wave/tile.
// EPI 2: outf[idx] = relu(acc + e0[col]); EPI 3: outf[idx] = acc (partial).
template <int FM, int FN, int EPI, int DEPTH>
__device__ __forceinline__ void gemm_core(
    const unsigned short* __restrict__ A, const unsigned short* __restrict__ Bt,
    int N, int lda, int kchunk, const float* __restrict__ e0,
    float* __restrict__ outf, int nwg, int bid) {
  constexpr int BM = 32 * FM, BN = 32 * FN, BK = 64;
  constexpr int AI = FM, BI = FN;       // 1KB staging issues per wave
  constexpr int ISS = AI + BI;
  __shared__ unsigned short lds[DEPTH][(BM + BN) * BK];

  const int tid = threadIdx.x;
  const int wid = tid >> 6;
  const int lane = tid & 63;
  const int wr = wid >> 1, wc = wid & 1;

  // XCD-aware bijective swizzle (nwg % 8 == 0)
  const int swz = (bid & 7) * (nwg >> 3) + (bid >> 3);
  const int nbn = N / BN;
  const int brow = (swz / nbn) * BM;
  const int bcol = (swz % nbn) * BN;

  f32x4 zero = {0.f, 0.f, 0.f, 0.f};
  f32x4 acc[FM][FN];
#pragma unroll
  for (int m = 0; m < FM; ++m)
#pragma unroll
    for (int n = 0; n < FN; ++n) acc[m][n] = zero;

  const int lr = lane >> 3;
  const int swzc = ((lane & 7) ^ lr) * 8;     // pre-swizzled source col (elems)
  const unsigned short* Agh = A + (size_t)(brow + wid * (BM / 4) + lr) * lda + swzc;
  const unsigned short* Bgh = Bt + (size_t)(bcol + wid * (BN / 4) + lr) * lda + swzc;

  const int frow = lane & 15;
  const int fhi = lane >> 4;

  const int nsteps = kchunk / BK;   // >= DEPTH for all our shapes

  auto stage = [&](int b, int kofs) {   // kofs in ELEMENTS (t*BK)
    unsigned short* AsW = lds[b] + wid * (BM / 4) * 64;
#pragma unroll
    for (int i = 0; i < AI; ++i)
      gload_lds16(Agh + kofs + (size_t)(8 * i) * lda, AsW + i * 512);
    unsigned short* BsW = lds[b] + BM * BK + wid * (BN / 4) * 64;
#pragma unroll
    for (int i = 0; i < BI; ++i)
      gload_lds16(Bgh + kofs + (size_t)(8 * i) * lda, BsW + i * 512);
  };

  auto compute = [&](int cur) {
    const unsigned short* As = lds[cur];
    const unsigned short* Bs = lds[cur] + BM * BK;
#pragma unroll
    for (int ks = 0; ks < 2; ++ks) {
      bf16x8 af[FM], bg[FN];
#pragma unroll
      for (int m = 0; m < FM; ++m) {
        int row = wr * FM * 16 + m * 16 + frow;
        int pc = (ks * 4 + fhi) ^ (row & 7);
        af[m] = *reinterpret_cast<const bf16x8*>(As + row * 64 + pc * 8);
      }
#pragma unroll
      for (int n = 0; n < FN; ++n) {
        int row = wc * FN * 16 + n * 16 + frow;
        int pc = (ks * 4 + fhi) ^ (row & 7);
        bg[n] = *reinterpret_cast<const bf16x8*>(Bs + row * 64 + pc * 8);
      }
#pragma unroll
      for (int m = 0; m < FM; ++m)
#pragma unroll
        for (int n = 0; n < FN; ++n)
          acc[m][n] = __builtin_amdgcn_mfma_f32_16x16x32_bf16(af[m], bg[n],
                                                              acc[m][n], 0, 0, 0);
    }
  };

  // prologue: DEPTH tiles in flight
#pragma unroll
  for (int d = 0; d < DEPTH; ++d) stage(d, d * BK);

  int cur = 0;
  for (int t = 0; t < nsteps; ++t) {
    const int ahead = nsteps - 1 - t;     // stages outstanding beyond tile t
    if (ahead >= DEPTH - 1)
      waitvm<(DEPTH - 1) * ISS>();        // tile t landed (my portion)
    else
      waitvm<0>();
    barrier_fence();                      // ...for all waves
    compute(cur);
    if (t + 1 < nsteps) {
      asm volatile("s_waitcnt lgkmcnt(0)" ::: "memory");
      barrier_fence();                    // all waves done reading cur
      if (t + DEPTH < nsteps) stage(cur, (t + DEPTH) * BK);
    }
    cur = (cur + 1 == DEPTH) ? 0 : cur + 1;
  }

  // epilogue: D col = lane&15, row = (lane>>4)*4 + j
#pragma unroll
  for (int m = 0; m < FM; ++m) {
    int gr0 = brow + wr * FM * 16 + m * 16 + fhi * 4;
#pragma unroll
    for (int n = 0; n < FN; ++n) {
      int gc = bcol + wc * FN * 16 + n * 16 + frow;
#pragma unroll
      for (int j = 0; j < 4; ++j) {
        size_t idx = (size_t)(gr0 + j) * N + gc;
        float v = acc[m][n][j];
        if constexpr (EPI == 2) {
          v += e0[gc];
          outf[idx] = v > 0.f ? v : 0.f;
        } else {
          outf[idx] = v;
        }
      }
    }
  }
}

// ---- merged split-K partial GEMMs, all-bf16, 128x128 tiles ----
// blocks [0,256)   : inputs@U  (lda 4096, kchunk 1024, split 4) -> p1
// blocks [256,384) : context@W (lda 1024, kchunk  512, split 2) -> p0
// K-chunk offset applied to BOTH A and Bt.
__global__ __launch_bounds__(256) void gemm01_kernel(
    const unsigned short* __restrict__ inb, const unsigned short* __restrict__ Ut,
    const unsigned short* __restrict__ ctxb, const unsigned short* __restrict__ Wt,
    float* __restrict__ p0, float* __restrict__ p1) {
  const int bid = (int)blockIdx.x;
  constexpr size_t MN = (size_t)2048 * 512;
  if (bid < 256) {
    const int split = bid >> 6;          // 4 splits x 64 positions
    gemm_core<4, 4, 3, 2>(inb + (size_t)split * 1024,
                          Ut + (size_t)split * 1024,
                          512, 4096, 1024, nullptr,
                          p1 + split * MN, 64, bid & 63);
  } else {
    const int sb = bid - 256;
    const int split = sb >> 6;           // 2 splits x 64 positions
    gemm_core<4, 4, 3, 2>(ctxb + (size_t)split * 512,
                          Wt + (size_t)split * 512,
                          512, 1024, 512, nullptr,
                          p0 + split * MN, 64, sb & 63);
  }
}

// ---- final GEMM: out = relu(xus @ V^T + bias), 128x128 tiles ----
__global__ __launch_bounds__(256) void gemm2_kernel(
    const unsigned short* __restrict__ xus, const unsigned short* __restrict__ Vb,
    const float* __restrict__ bias, float* __restrict__ out) {
  gemm_core<4, 4, 2, 2>(xus, Vb, 4096, 512, 512, bias, out, 512,
                        (int)blockIdx.x);
}

// ---- fused split-K reduce: xus = bf16((sum p1) * (S + sum p0)) ----
__global__ void reduce_mul_kernel(const float* __restrict__ p1,  // [4][MN]
                                  const float* __restrict__ p0,  // [2][MN]
                                  const float* __restrict__ Svec,  // [512]
                                  unsigned short* __restrict__ xus, int MN) {
  int i = blockIdx.x * blockDim.x + threadIdx.x;
  size_t base = (size_t)i * 4;
  if (base >= (size_t)MN) return;
  float4 a = *reinterpret_cast<const float4*>(p1 + base);
  float4 b = *reinterpret_cast<const float4*>(p1 + (size_t)MN + base);
  float4 c = *reinterpret_cast<const float4*>(p1 + 2 * (size_t)MN + base);
  float4 d = *reinterpret_cast<const float4*>(p1 + 3 * (size_t)MN + base);
  float4 s0 = *reinterpret_cast<const float4*>(p0 + base);
  float4 s1 = *reinterpret_cast<const float4*>(p0 + (size_t)MN + base);
  float4 sv = *reinterpret_cast<const float4*>(Svec + (base & 511));
  float4 xu, s;
  xu.x = (a.x + b.x) + (c.x + d.x);  s.x = s0.x + s1.x + sv.x;
  xu.y = (a.y + b.y) + (c.y + d.y);  s.y = s0.y + s1.y + sv.y;
  xu.z = (a.z + b.z) + (c.z + d.z);  s.z = s0.z + s1.z + sv.z;
  xu.w = (a.w + b.w) + (c.w + d.w);  s.w = s0.w + s1.w + sv.w;
  ushort4v o;
  o[0] = f2bf(xu.x * s.x);
  o[1] = f2bf(xu.y * s.y);
  o[2] = f2bf(xu.z * s.z);
  o[3] = f2bf(xu.w * s.w);
  *reinterpret_cast<ushort4v*>(xus + base) = o;
}

extern "C" void kernel_launch(void* const* d_in, const int* in_sizes, int n_in,
                              void* d_out, int out_size, void* d_ws, size_t ws_size,
                              hipStream_t stream) {
  constexpr int Bm = 2048, Nn = 4096, Cc = 1024, UU = 4096, RR = 512;
  const float* inputs  = (const float*)d_in[0];
  const float* context = (const float*)d_in[1];
  const float* U       = (const float*)d_in[2];
  const float* S       = (const float*)d_in[3];
  const float* V       = (const float*)d_in[4];
  const float* W       = (const float*)d_in[5];
  const float* bias    = (const float*)d_in[6];
  float* out = (float*)d_out;

  char* p = (char*)d_ws;
  unsigned short* Ut   = (unsigned short*)p; p += (size_t)RR * Nn * 2;      //  4 MB
  unsigned short* Wt   = (unsigned short*)p; p += (size_t)RR * Cc * 2;      //  1 MB
  unsigned short* Vb   = (unsigned short*)p; p += (size_t)UU * RR * 2;      //  4 MB
  unsigned short* inb  = (unsigned short*)p; p += (size_t)Bm * Nn * 2;      // 16 MB
  unsigned short* ctxb = (unsigned short*)p; p += (size_t)Bm * Cc * 2;      //  4 MB
  float*          p0   = (float*)p;          p += (size_t)2 * Bm * RR * 4;  //  8 MB
  float*          p1   = (float*)p;          p += (size_t)4 * Bm * RR * 4;  // 16 MB
  unsigned short* xus  = (unsigned short*)p; p += (size_t)Bm * RR * 2;      //  2 MB

  // 1) prep: all conversions (U^T, W^T, V, inputs, context -> bf16)
  prep_kernel<<<8704, 256, 0, stream>>>(U, Ut, W, Wt, V, Vb, inputs, inb,
                                        context, ctxb);

  // 2) merged split-K partials (128x128 tiles, 4x4 frags/wave)
  gemm01_kernel<<<384, 256, 0, stream>>>(inb, Ut, ctxb, Wt, p0, p1);

  // 3) xus = bf16((sum p1) * (S + sum p0))
  reduce_mul_kernel<<<Bm * RR / 4 / 256, 256, 0, stream>>>(p1, p0, S, xus, Bm * RR);

  // 4) out = relu(xus @ V^T + bias)   (M=2048, N=4096, K=512, 128x128 tiles)
  gemm2_kernel<<<512, 256, 0, stream>>>(xus, Vb, bias, out);
}

// Round 14
// 52.102 us; speedup vs baseline: 1.3824x; 1.0403x over previous
//
#include <hip/hip_runtime.h>
#include <hip/hip_bf16.h>

typedef __attribute__((ext_vector_type(8))) __bf16 bf16x8;
typedef __attribute__((ext_vector_type(4))) float f32x4;
typedef __attribute__((ext_vector_type(8))) unsigned short ushort8;
typedef __attribute__((ext_vector_type(4))) unsigned short ushort4v;

__device__ __forceinline__ unsigned short f2bf(float f) {
  unsigned u = __builtin_bit_cast(unsigned, f);
  u += 0x7FFFu + ((u >> 16) & 1u);   // round-to-nearest-even
  return (unsigned short)(u >> 16);
}

__device__ __forceinline__ void gload_lds16(const void* g, void* l) {
  __builtin_amdgcn_global_load_lds(
      (const __attribute__((address_space(1))) void*)g,
      (__attribute__((address_space(3))) void*)l, 16, 0, 0);
}

__device__ __forceinline__ void barrier_fence() {
  __builtin_amdgcn_s_barrier();
  asm volatile("" ::: "memory");
}

template <int N>
__device__ __forceinline__ void waitvm() {
  if constexpr (N == 0)      asm volatile("s_waitcnt vmcnt(0)" ::: "memory");
  else if constexpr (N == 8) asm volatile("s_waitcnt vmcnt(8)" ::: "memory");
}

// ---- prep: weight conversions only ----
// [0,2048)    : U[4096][512] -> Ut[512][4096] bf16 (transpose)
// [2048,2560) : W[1024][512] -> Wt[512][1024] bf16 (transpose)
// [2560,3584) : V   (2M f32) -> Vb bf16
__global__ __launch_bounds__(256) void prep_kernel(
    const float* __restrict__ U, unsigned short* __restrict__ Ut,
    const float* __restrict__ W, unsigned short* __restrict__ Wt,
    const float* __restrict__ V, unsigned short* __restrict__ Vb) {
  __shared__ float tile[32][33];
  const int b = blockIdx.x;
  const int tid = threadIdx.x;
  if (b < 2560) {
    const float* src;
    unsigned short* dst;
    int rows, cols, bx, by;
    if (b < 2048) {
      src = U; dst = Ut; rows = 4096; cols = 512;
      bx = (b & 15) * 32; by = (b >> 4) * 32;
    } else {
      int bb = b - 2048;
      src = W; dst = Wt; rows = 1024; cols = 512;
      bx = (bb & 15) * 32; by = (bb >> 4) * 32;
    }
    const int tx = tid & 31, ty = tid >> 5;
    for (int i = ty; i < 32; i += 8)
      tile[i][tx] = src[(size_t)(by + i) * cols + bx + tx];
    __syncthreads();
    for (int i = ty; i < 32; i += 8)
      dst[(size_t)(bx + i) * rows + by + tx] = f2bf(tile[tx][i]);
  } else {
    const size_t i = (size_t)(b - 2560) * 256 + tid;  // 8 f32 per thread
    const float4* s4 = reinterpret_cast<const float4*>(V) + 2 * i;
    float4 a = s4[0], c = s4[1];
    ushort8 o;
    o[0] = f2bf(a.x); o[1] = f2bf(a.y); o[2] = f2bf(a.z); o[3] = f2bf(a.w);
    o[4] = f2bf(c.x); o[5] = f2bf(c.y); o[6] = f2bf(c.z); o[7] = f2bf(c.w);
    *(reinterpret_cast<ushort8*>(Vb) + i) = o;
  }
}

// ======== bf16 GEMM core (gemm2): 128x128, counted-vmcnt DEPTH=2 ========
// Byte-identical behavior to round 13 (proven).  A,Bt bf16 via global_load_lds.
// Caller passes A and Bt already offset to the K-chunk start.
// EPI 2: outf[idx] = relu(acc + e0[col]); EPI 3: outf[idx] = acc (partial).
template <int FM, int FN, int EPI, int DEPTH>
__device__ __forceinline__ void gemm_core(
    const unsigned short* __restrict__ A, const unsigned short* __restrict__ Bt,
    int N, int lda, int kchunk, const float* __restrict__ e0,
    float* __restrict__ outf, int nwg, int bid) {
  constexpr int BM = 32 * FM, BN = 32 * FN, BK = 64;
  constexpr int AI = FM, BI = FN;
  constexpr int ISS = AI + BI;
  __shared__ unsigned short lds[DEPTH][(BM + BN) * BK];

  const int tid = threadIdx.x;
  const int wid = tid >> 6;
  const int lane = tid & 63;
  const int wr = wid >> 1, wc = wid & 1;

  const int swz = (bid & 7) * (nwg >> 3) + (bid >> 3);
  const int nbn = N / BN;
  const int brow = (swz / nbn) * BM;
  const int bcol = (swz % nbn) * BN;

  f32x4 zero = {0.f, 0.f, 0.f, 0.f};
  f32x4 acc[FM][FN];
#pragma unroll
  for (int m = 0; m < FM; ++m)
#pragma unroll
    for (int n = 0; n < FN; ++n) acc[m][n] = zero;

  const int lr = lane >> 3;
  const int swzc = ((lane & 7) ^ lr) * 8;
  const unsigned short* Agh = A + (size_t)(brow + wid * (BM / 4) + lr) * lda + swzc;
  const unsigned short* Bgh = Bt + (size_t)(bcol + wid * (BN / 4) + lr) * lda + swzc;

  const int frow = lane & 15;
  const int fhi = lane >> 4;

  const int nsteps = kchunk / BK;

  auto stage = [&](int b, int kofs) {
    unsigned short* AsW = lds[b] + wid * (BM / 4) * 64;
#pragma unroll
    for (int i = 0; i < AI; ++i)
      gload_lds16(Agh + kofs + (size_t)(8 * i) * lda, AsW + i * 512);
    unsigned short* BsW = lds[b] + BM * BK + wid * (BN / 4) * 64;
#pragma unroll
    for (int i = 0; i < BI; ++i)
      gload_lds16(Bgh + kofs + (size_t)(8 * i) * lda, BsW + i * 512);
  };

  auto compute = [&](int cur) {
    const unsigned short* As = lds[cur];
    const unsigned short* Bs = lds[cur] + BM * BK;
#pragma unroll
    for (int ks = 0; ks < 2; ++ks) {
      bf16x8 af[FM], bg[FN];
#pragma unroll
      for (int m = 0; m < FM; ++m) {
        int row = wr * FM * 16 + m * 16 + frow;
        int pc = (ks * 4 + fhi) ^ (row & 7);
        af[m] = *reinterpret_cast<const bf16x8*>(As + row * 64 + pc * 8);
      }
#pragma unroll
      for (int n = 0; n < FN; ++n) {
        int row = wc * FN * 16 + n * 16 + frow;
        int pc = (ks * 4 + fhi) ^ (row & 7);
        bg[n] = *reinterpret_cast<const bf16x8*>(Bs + row * 64 + pc * 8);
      }
#pragma unroll
      for (int m = 0; m < FM; ++m)
#pragma unroll
        for (int n = 0; n < FN; ++n)
          acc[m][n] = __builtin_amdgcn_mfma_f32_16x16x32_bf16(af[m], bg[n],
                                                              acc[m][n], 0, 0, 0);
    }
  };

#pragma unroll
  for (int d = 0; d < DEPTH; ++d) stage(d, d * BK);

  int cur = 0;
  for (int t = 0; t < nsteps; ++t) {
    const int ahead = nsteps - 1 - t;
    if (ahead >= DEPTH - 1)
      waitvm<(DEPTH - 1) * ISS>();
    else
      waitvm<0>();
    barrier_fence();
    compute(cur);
    if (t + 1 < nsteps) {
      asm volatile("s_waitcnt lgkmcnt(0)" ::: "memory");
      barrier_fence();
      if (t + DEPTH < nsteps) stage(cur, (t + DEPTH) * BK);
    }
    cur = (cur + 1 == DEPTH) ? 0 : cur + 1;
  }

#pragma unroll
  for (int m = 0; m < FM; ++m) {
    int gr0 = brow + wr * FM * 16 + m * 16 + fhi * 4;
#pragma unroll
    for (int n = 0; n < FN; ++n) {
      int gc = bcol + wc * FN * 16 + n * 16 + frow;
#pragma unroll
      for (int j = 0; j < 4; ++j) {
        size_t idx = (size_t)(gr0 + j) * N + gc;
        float v = acc[m][n][j];
        if constexpr (EPI == 2) {
          v += e0[gc];
          outf[idx] = v > 0.f ? v : 0.f;
        } else {
          outf[idx] = v;
        }
      }
    }
  }
}

// ======== f32-A GEMM core (gemm01): 128x128, fused cvt, 1 barrier/step ======
// A f32 in HBM -> 8 dwordx4/wave/tile to regs -> f2bf -> 4 ds_write_b128 into
// the SAME XOR-swizzled bf16 LDS layout.  B bf16 via global_load_lds.
// Step t: bload(t+1) | compute(t) | vmcnt(0) [A(t+1) regs + B(t+1) landed,
// mine] | awrite(t+1) | aload(t+2) | lgkm(0) | barrier.
// Every cross-wave-consumed datum is per-wave-waited before the barrier.
// Buffer hazards: bload/awrite(t+1) target buf[(t+1)&1], whose readers
// (compute(t-1)) drained (lgkm0) before the previous barrier.
// Output: partial (EPI 3 semantics).
__device__ __forceinline__ void gemm_core_f32a(
    const float* __restrict__ A, const unsigned short* __restrict__ Bt,
    int lda, int kchunk, float* __restrict__ outf, int nwg, int bid) {
  constexpr int N = 512;
  constexpr int BM = 128, BN = 128, BK = 64;
  __shared__ unsigned short lds[2][(BM + BN) * BK];  // 2 x 32 KB

  const int tid = threadIdx.x;
  const int wid = tid >> 6;
  const int lane = tid & 63;
  const int wr = wid >> 1, wc = wid & 1;

  const int swz = (bid & 7) * (nwg >> 3) + (bid >> 3);
  const int nbn = N / BN;        // 4
  const int brow = (swz / nbn) * BM;
  const int bcol = (swz % nbn) * BN;

  f32x4 zero = {0.f, 0.f, 0.f, 0.f};
  f32x4 acc[4][4];
#pragma unroll
  for (int m = 0; m < 4; ++m)
#pragma unroll
    for (int n = 0; n < 4; ++n) acc[m][n] = zero;

  const int lr = lane >> 3;      // 0..7
  const int lc = lane & 7;       // phys 16B chunk
  const int swzc = (lc ^ lr) * 8;  // logical col base for phys chunk lc, row lr
  // A: lane covers rows {wid*32 + i*8 + lr}, global cols swzc..swzc+7 (2xfloat4)
  const float* Agf = A + (size_t)(brow + wid * 32 + lr) * lda + swzc;
  const unsigned short* Bgh = Bt + (size_t)(bcol + wid * 32 + lr) * lda + swzc;

  const int frow = lane & 15;
  const int fhi = lane >> 4;

  const int nsteps = kchunk / BK;  // >= 2

  float4 areg[4][2];
  auto aload = [&](int kofs) {
#pragma unroll
    for (int i = 0; i < 4; ++i) {
      const float* s = Agf + kofs + (size_t)(8 * i) * lda;
      areg[i][0] = *reinterpret_cast<const float4*>(s);
      areg[i][1] = *reinterpret_cast<const float4*>(s + 4);
    }
  };
  auto awrite = [&](int b) {
    unsigned short* AsW = lds[b] + wid * 2048 + lane * 8;
#pragma unroll
    for (int i = 0; i < 4; ++i) {
      float4 x = areg[i][0], y = areg[i][1];
      ushort8 o;
      o[0] = f2bf(x.x); o[1] = f2bf(x.y); o[2] = f2bf(x.z); o[3] = f2bf(x.w);
      o[4] = f2bf(y.x); o[5] = f2bf(y.y); o[6] = f2bf(y.z); o[7] = f2bf(y.w);
      *reinterpret_cast<ushort8*>(AsW + i * 512) = o;
    }
  };
  auto bload = [&](int b, int kofs) {
    unsigned short* BsW = lds[b] + BM * BK + wid * 2048;
#pragma unroll
    for (int i = 0; i < 4; ++i)
      gload_lds16(Bgh + kofs + (size_t)(8 * i) * lda, BsW + i * 512);
  };

  auto compute = [&](int cur) {
    const unsigned short* As = lds[cur];
    const unsigned short* Bs = lds[cur] + BM * BK;
#pragma unroll
    for (int ks = 0; ks < 2; ++ks) {
      bf16x8 af[4], bg[4];
#pragma unroll
      for (int m = 0; m < 4; ++m) {
        int row = wr * 64 + m * 16 + frow;
        int pc = (ks * 4 + fhi) ^ (row & 7);
        af[m] = *reinterpret_cast<const bf16x8*>(As + row * 64 + pc * 8);
      }
#pragma unroll
      for (int n = 0; n < 4; ++n) {
        int row = wc * 64 + n * 16 + frow;
        int pc = (ks * 4 + fhi) ^ (row & 7);
        bg[n] = *reinterpret_cast<const bf16x8*>(Bs + row * 64 + pc * 8);
      }
#pragma unroll
      for (int m = 0; m < 4; ++m)
#pragma unroll
        for (int n = 0; n < 4; ++n)
          acc[m][n] = __builtin_amdgcn_mfma_f32_16x16x32_bf16(af[m], bg[n],
                                                              acc[m][n], 0, 0, 0);
    }
  };

  // prologue: A(0)+B(0) staged & written; A(1) in flight to regs
  aload(0);
  bload(0, 0);
  waitvm<0>();
  awrite(0);
  aload(BK);          // A(1) -> regs (WAR on areg handled by compiler)
  asm volatile("s_waitcnt lgkmcnt(0)" ::: "memory");
  barrier_fence();

  for (int t = 0; t < nsteps; ++t) {
    const int cur = t & 1;
    if (t + 1 < nsteps) bload(cur ^ 1, (t + 1) * BK);
    compute(cur);
    if (t + 1 < nsteps) {
      waitvm<0>();     // my A(t+1) regs + my B(t+1) portion landed
      awrite(cur ^ 1);
      if (t + 2 < nsteps) aload((t + 2) * BK);
      asm volatile("s_waitcnt lgkmcnt(0)" ::: "memory");  // ds_writes + reads
      barrier_fence(); // tile t+1 fully in LDS for all waves
    }
  }

  // epilogue: partial write (EPI 3)
#pragma unroll
  for (int m = 0; m < 4; ++m) {
    int gr0 = brow + wr * 64 + m * 16 + fhi * 4;
#pragma unroll
    for (int n = 0; n < 4; ++n) {
      int gc = bcol + wc * 64 + n * 16 + frow;
#pragma unroll
      for (int j = 0; j < 4; ++j)
        outf[(size_t)(gr0 + j) * N + gc] = acc[m][n][j];
    }
  }
}

// ---- merged split-K partial GEMMs, f32 A fused-cvt, 128x128 tiles ----
// blocks [0,256)   : inputs@U  (lda 4096, kchunk 1024, split 4) -> p1
// blocks [256,384) : context@W (lda 1024, kchunk  512, split 2) -> p0
// K-chunk offset applied to BOTH A and Bt.
__global__ __launch_bounds__(256) void gemm01_kernel(
    const float* __restrict__ inp, const unsigned short* __restrict__ Ut,
    const float* __restrict__ ctx, const unsigned short* __restrict__ Wt,
    float* __restrict__ p0, float* __restrict__ p1) {
  const int bid = (int)blockIdx.x;
  constexpr size_t MN = (size_t)2048 * 512;
  if (bid < 256) {
    const int split = bid >> 6;          // 4 splits x 64 positions
    gemm_core_f32a(inp + (size_t)split * 1024, Ut + (size_t)split * 1024,
                   4096, 1024, p1 + split * MN, 64, bid & 63);
  } else {
    const int sb = bid - 256;
    const int split = sb >> 6;           // 2 splits x 64 positions
    gemm_core_f32a(ctx + (size_t)split * 512, Wt + (size_t)split * 512,
                   1024, 512, p0 + split * MN, 64, sb & 63);
  }
}

// ---- final GEMM: out = relu(xus @ V^T + bias), 128x128 tiles ----
__global__ __launch_bounds__(256) void gemm2_kernel(
    const unsigned short* __restrict__ xus, const unsigned short* __restrict__ Vb,
    const float* __restrict__ bias, float* __restrict__ out) {
  gemm_core<4, 4, 2, 2>(xus, Vb, 4096, 512, 512, bias, out, 512,
                        (int)blockIdx.x);
}

// ---- fused split-K reduce: xus = bf16((sum p1) * (S + sum p0)) ----
__global__ void reduce_mul_kernel(const float* __restrict__ p1,  // [4][MN]
                                  const float* __restrict__ p0,  // [2][MN]
                                  const float* __restrict__ Svec,  // [512]
                                  unsigned short* __restrict__ xus, int MN) {
  int i = blockIdx.x * blockDim.x + threadIdx.x;
  size_t base = (size_t)i * 4;
  if (base >= (size_t)MN) return;
  float4 a = *reinterpret_cast<const float4*>(p1 + base);
  float4 b = *reinterpret_cast<const float4*>(p1 + (size_t)MN + base);
  float4 c = *reinterpret_cast<const float4*>(p1 + 2 * (size_t)MN + base);
  float4 d = *reinterpret_cast<const float4*>(p1 + 3 * (size_t)MN + base);
  float4 s0 = *reinterpret_cast<const float4*>(p0 + base);
  float4 s1 = *reinterpret_cast<const float4*>(p0 + (size_t)MN + base);
  float4 sv = *reinterpret_cast<const float4*>(Svec + (base & 511));
  float4 xu, s;
  xu.x = (a.x + b.x) + (c.x + d.x);  s.x = s0.x + s1.x + sv.x;
  xu.y = (a.y + b.y) + (c.y + d.y);  s.y = s0.y + s1.y + sv.y;
  xu.z = (a.z + b.z) + (c.z + d.z);  s.z = s0.z + s1.z + sv.z;
  xu.w = (a.w + b.w) + (c.w + d.w);  s.w = s0.w + s1.w + sv.w;
  ushort4v o;
  o[0] = f2bf(xu.x * s.x);
  o[1] = f2bf(xu.y * s.y);
  o[2] = f2bf(xu.z * s.z);
  o[3] = f2bf(xu.w * s.w);
  *reinterpret_cast<ushort4v*>(xus + base) = o;
}

extern "C" void kernel_launch(void* const* d_in, const int* in_sizes, int n_in,
                              void* d_out, int out_size, void* d_ws, size_t ws_size,
                              hipStream_t stream) {
  constexpr int Bm = 2048, Nn = 4096, Cc = 1024, UU = 4096, RR = 512;
  const float* inputs  = (const float*)d_in[0];
  const float* context = (const float*)d_in[1];
  const float* U       = (const float*)d_in[2];
  const float* S       = (const float*)d_in[3];
  const float* V       = (const float*)d_in[4];
  const float* W       = (const float*)d_in[5];
  const float* bias    = (const float*)d_in[6];
  float* out = (float*)d_out;

  char* p = (char*)d_ws;
  unsigned short* Ut   = (unsigned short*)p; p += (size_t)RR * Nn * 2;      //  4 MB
  unsigned short* Wt   = (unsigned short*)p; p += (size_t)RR * Cc * 2;      //  1 MB
  unsigned short* Vb   = (unsigned short*)p; p += (size_t)UU * RR * 2;      //  4 MB
  float*          p0   = (float*)p;          p += (size_t)2 * Bm * RR * 4;  //  8 MB
  float*          p1   = (float*)p;          p += (size_t)4 * Bm * RR * 4;  // 16 MB
  unsigned short* xus  = (unsigned short*)p; p += (size_t)Bm * RR * 2;      //  2 MB

  // 1) prep: U^T, W^T, V -> bf16 (inputs/context conversion fused into gemm01)
  prep_kernel<<<3584, 256, 0, stream>>>(U, Ut, W, Wt, V, Vb);

  // 2) merged split-K partials from f32 A (128x128 tiles, fused cvt)
  gemm01_kernel<<<384, 256, 0, stream>>>(inputs, Ut, context, Wt, p0, p1);

  // 3) xus = bf16((sum p1) * (S + sum p0))
  reduce_mul_kernel<<<Bm * RR / 4 / 256, 256, 0, stream>>>(p1, p0, S, xus, Bm * RR);

  // 4) out = relu(xus @ V^T + bias)   (M=2048, N=4096, K=512, 128x128 tiles)
  gemm2_kernel<<<512, 256, 0, stream>>>(xus, Vb, bias, out);
}